// Round 1
// baseline (629.779 us; speedup 1.0000x reference)
//
#include <hip/hip_runtime.h>
#include <hip/hip_bf16.h>
#include <cstdint>
#include <cstddef>

#define TT 128
#define BBATCH 256
#define FFEAT 76
#define HDIM 64
#define NHEAD 4
#define DKH 16
#define DFF1 256
#define AH1 8
#define NROWS (BBATCH * FFEAT)   // 19456

#define LOG2E 1.4426950408889634f

typedef __attribute__((ext_vector_type(8))) short bf16x8;
typedef __attribute__((ext_vector_type(4))) float f32x4;

__device__ __forceinline__ float fast_sigmoid(float v) {
    float p = __builtin_amdgcn_exp2f(-v * LOG2E);
    return __builtin_amdgcn_rcpf(1.0f + p);
}
__device__ __forceinline__ float fast_tanh(float v) {
    float p = __builtin_amdgcn_exp2f(v * (2.0f * LOG2E));
    return 1.0f - 2.0f * __builtin_amdgcn_rcpf(1.0f + p);
}
__device__ __forceinline__ short f2bf(float x) {
    __hip_bfloat16 h = __float2bfloat16(x);
    return *reinterpret_cast<short*>(&h);
}
__device__ __forceinline__ float bf2f(unsigned short s) {
    return __uint_as_float(((unsigned)s) << 16);
}
__device__ __forceinline__ unsigned pack_bf16(float a, float b) {
    unsigned ua = (unsigned)(unsigned short)f2bf(a);
    unsigned ub = (unsigned)(unsigned short)f2bf(b);
    return ua | (ub << 16);
}

// ---------------------------------------------------------------------------
// Kernel 1: ZERO-EXCHANGE GRU scan (UNCHANGED from previous round).
// ---------------------------------------------------------------------------
__global__ __launch_bounds__(256, 1) void gru_scan_kernel(
    const float* __restrict__ x, const float* __restrict__ w_ih,
    const float* __restrict__ w_hh, const float* __restrict__ b_ih,
    const float* __restrict__ b_hh, const float* __restrict__ Wt,
    const float* __restrict__ Wx, int f_base,
    __hip_bfloat16* __restrict__ hs, float* __restrict__ wtil)
{
    const int f_loc = blockIdx.y;
    const int f     = f_base + f_loc;
    const int bblk  = blockIdx.x * 64;
    const int tid   = threadIdx.x;
    const int wave  = tid >> 6;
    const int lane  = tid & 63;
    const int c     = lane & 15;
    const int q     = lane >> 4;
    const int b0    = bblk + wave * 16;

    __shared__ float x_lds[TT][64];
    __shared__ float wt_s[64][8];
    __shared__ float wx_s[64][8];
    __shared__ short hx[4][16][72];
    __shared__ float q_s[4][16][8];

    for (int i = tid; i < TT * 64; i += 256) {
        int t = i >> 6, b = i & 63;
        x_lds[t][b] = x[((size_t)t * BBATCH + bblk + b) * FFEAT + f];
    }
    for (int i = tid; i < 512; i += 256) {
        ((float*)wt_s)[i] = Wt[(size_t)f * 512 + i];
        ((float*)wx_s)[i] = Wx[(size_t)f * 512 + i];
    }
    __syncthreads();   // the ONLY block barrier

    bf16x8 afr[12][2];
    {
        const float* whh_f = w_hh + (size_t)f * 192 * 64;
        #pragma unroll
        for (int nt = 0; nt < 12; ++nt) {
            int gate = nt >> 2, tt = nt & 3;
            int urow = (c >> 2) * 8 + (tt & 1) * 4 + (c & 3) + (tt >> 1) * 32;
            const float* row = whh_f + (size_t)(gate * 64 + urow) * 64;
            #pragma unroll
            for (int kq = 0; kq < 2; ++kq) {
                bf16x8 fr;
                #pragma unroll
                for (int j = 0; j < 8; ++j) fr[j] = f2bf(row[kq * 32 + q * 8 + j]);
                afr[nt][kq] = fr;
            }
        }
    }
    float wr[4][4], wz[4][4], wn[4][4], bnx[4][4];
    f32x4 biasv[12];
    #pragma unroll
    for (int tt = 0; tt < 4; ++tt) {
        #pragma unroll
        for (int r = 0; r < 4; ++r) {
            int u = q * 8 + (tt & 1) * 4 + r + (tt >> 1) * 32;
            wr[tt][r]  = w_ih[f*192 + u];
            wz[tt][r]  = w_ih[f*192 + 64 + u];
            wn[tt][r]  = w_ih[f*192 + 128 + u];
            bnx[tt][r] = b_ih[f*192 + 128 + u];
            biasv[tt][r]     = b_ih[f*192 + u]      + b_hh[f*192 + u];
            biasv[4 + tt][r] = b_ih[f*192 + 64 + u] + b_hh[f*192 + 64 + u];
            biasv[8 + tt][r] = b_hh[f*192 + 128 + u];
        }
    }

    float hprev[4][4];
    #pragma unroll
    for (int tt = 0; tt < 4; ++tt)
        #pragma unroll
        for (int r = 0; r < 4; ++r) hprev[tt][r] = 0.f;

    bf16x8 hb0 = {0,0,0,0,0,0,0,0};
    bf16x8 hb1 = {0,0,0,0,0,0,0,0};

    short* hs_b = (short*)hs + ((size_t)f_loc * BBATCH + b0 + c) * TT * HDIM;

    for (int t = 0; t < TT; ++t) {
        f32x4 acc[12];
        #pragma unroll
        for (int nt = 0; nt < 12; ++nt) {
            f32x4 a = __builtin_amdgcn_mfma_f32_16x16x32_bf16(afr[nt][0], hb0, biasv[nt], 0, 0, 0);
            acc[nt]  = __builtin_amdgcn_mfma_f32_16x16x32_bf16(afr[nt][1], hb1, a, 0, 0, 0);
        }

        float xv = x_lds[t][wave * 16 + c];
        float hn4[4][4];
        #pragma unroll
        for (int tt = 0; tt < 4; ++tt) {
            #pragma unroll
            for (int r = 0; r < 4; ++r) {
                float R  = fmaf(xv, wr[tt][r], acc[tt][r]);
                float Z  = fmaf(xv, wz[tt][r], acc[4 + tt][r]);
                float NX = fmaf(xv, wn[tt][r], bnx[tt][r]);
                float rg = fast_sigmoid(R);
                float zg = fast_sigmoid(Z);
                float ng = fast_tanh(fmaf(rg, acc[8 + tt][r], NX));
                float hn = fmaf(zg, hprev[tt][r] - ng, ng);
                hprev[tt][r] = hn;
                hn4[tt][r] = hn;
            }
        }
        {
            union { int4 i; bf16x8 v; } u0, u1;
            u0.i.x = pack_bf16(hn4[0][0], hn4[0][1]);
            u0.i.y = pack_bf16(hn4[0][2], hn4[0][3]);
            u0.i.z = pack_bf16(hn4[1][0], hn4[1][1]);
            u0.i.w = pack_bf16(hn4[1][2], hn4[1][3]);
            u1.i.x = pack_bf16(hn4[2][0], hn4[2][1]);
            u1.i.y = pack_bf16(hn4[2][2], hn4[2][3]);
            u1.i.z = pack_bf16(hn4[3][0], hn4[3][1]);
            u1.i.w = pack_bf16(hn4[3][2], hn4[3][3]);
            hb0 = u0.v; hb1 = u1.v;
        }
        short* dst = hs_b + (size_t)t * HDIM + q * 8;
        *(bf16x8*)dst = hb0;
        *(bf16x8*)(dst + 32) = hb1;
    }

    *(bf16x8*)&hx[wave][c][q * 8]      = hb0;
    *(bf16x8*)&hx[wave][c][32 + q * 8] = hb1;

    #pragma unroll
    for (int rr = 0; rr < 2; ++rr) {
        int role = rr * 64 + lane;
        int b = role >> 3, a = role & 7;
        float s = 0.f;
        #pragma unroll 8
        for (int j = 0; j < 64; ++j)
            s = fmaf(bf2f((unsigned short)hx[wave][b][j]), wt_s[j][a], s);
        q_s[wave][b][a] = s;
    }
    {
        int b = lane >> 2, jb = (lane & 3) * 16;
        float qreg[8];
        #pragma unroll
        for (int a = 0; a < 8; ++a) qreg[a] = q_s[wave][b][a];
        float* wt_out = wtil + ((size_t)(b0 + b) * FFEAT + f) * HDIM + jb;
        #pragma unroll
        for (int j4 = 0; j4 < 4; ++j4) {
            float4 v;
            #pragma unroll
            for (int jj = 0; jj < 4; ++jj) {
                int j = jb + j4 * 4 + jj;
                float s = 0.f;
                #pragma unroll
                for (int a = 0; a < 8; ++a) s = fmaf(wx_s[j][a], qreg[a], s);
                (&v.x)[jj] = s;
            }
            *(float4*)&wt_out[j4 * 4] = v;
        }
    }
}

// ---------------------------------------------------------------------------
// Kernel 2: time attention (UNCHANGED from previous round).
// ---------------------------------------------------------------------------
__global__ __launch_bounds__(64) void attn2_kernel(
    const __hip_bfloat16* __restrict__ hs, const float* __restrict__ wtil,
    const float* __restrict__ rate, int f_base, float* __restrict__ emb)
{
    const int b     = blockIdx.x;
    const int f_loc = blockIdx.y;
    const int f     = f_base + f_loc;
    const int lane  = threadIdx.x;

    __shared__ short h_s[TT][72];
    __shared__ float a_s[TT];

    float wreg[64];
    {
        const float4* src = (const float4*)(wtil + ((size_t)b * FFEAT + f) * HDIM);
        #pragma unroll
        for (int i = 0; i < 16; ++i) {
            float4 v = src[i];
            wreg[4*i+0] = v.x; wreg[4*i+1] = v.y; wreg[4*i+2] = v.z; wreg[4*i+3] = v.w;
        }
    }
    const float rs = fast_sigmoid(rate[f]);
    const short* base = (const short*)hs + ((size_t)f_loc * BBATCH + b) * TT * HDIM;

    float e[2];
    #pragma unroll
    for (int half = 0; half < 2; ++half) {
        int t = half * 64 + lane;
        const uint4* row = (const uint4*)(base + (size_t)t * HDIM);
        float dp = 0.f;
        #pragma unroll
        for (int c4 = 0; c4 < 8; ++c4) {
            uint4 u = row[c4];
            *(uint4*)&h_s[t][c4 * 8] = u;
            unsigned vals[4] = {u.x, u.y, u.z, u.w};
            #pragma unroll
            for (int p = 0; p < 4; ++p) {
                dp = fmaf(__uint_as_float(vals[p] << 16),         wreg[c4*8 + 2*p],     dp);
                dp = fmaf(__uint_as_float(vals[p] & 0xffff0000u), wreg[c4*8 + 2*p + 1], dp);
            }
        }
        float sig = fast_sigmoid(dp);
        float den = rs * (__logf(2.72f + (1.0f - sig)) * (float)(TT - t));
        e[half] = fmaxf(sig / den, 0.0f);
    }
    float m = fmaxf(e[0], e[1]);
    #pragma unroll
    for (int off = 32; off > 0; off >>= 1) m = fmaxf(m, __shfl_xor(m, off, 64));
    float p0 = __builtin_amdgcn_exp2f((e[0] - m) * LOG2E);
    float p1 = __builtin_amdgcn_exp2f((e[1] - m) * LOG2E);
    float s = p0 + p1;
    #pragma unroll
    for (int off = 32; off > 0; off >>= 1) s += __shfl_xor(s, off, 64);
    float inv = __builtin_amdgcn_rcpf(s);
    a_s[lane]      = p0 * inv;
    a_s[lane + 64] = p1 * inv;

    const int j = lane;
    float acc = 0.f;
    #pragma unroll 8
    for (int t = 0; t < TT; ++t)
        acc = fmaf(a_s[t], bf2f((unsigned short)h_s[t][j]), acc);
    emb[((size_t)b * FFEAT + f) * HDIM + j] = acc;
}

// ---------------------------------------------------------------------------
// Kernel 3 (NEW): fused per-batch tail. One block per batch. Everything from
// emb -> QKV -> MHA -> WO+res -> FFN+res -> final attention -> output head
// stays in one 143 KB LDS pool; weight tiles staged as 64x64 LDS slabs.
// Replaces 7 launches (5x gemm, mha_core, final) and all intermediate
// global round-trips (q,k,v,ctx,ctx2,hid,ctx3,fk,fv).
// ---------------------------------------------------------------------------
#define PSTR 65                 // padded row stride for 64-col tiles (bank-conflict-free)
#define OFF_EMB 0               // 76x65  (dead after S3)
#define OFF_Q   4940            // 76x65  (dead after S2)
#define OFF_K   9880            // 76x65  (dead after S2)
#define OFF_V   14820           // 76x65  (dead after S2)
#define OFF_SC  19760           // 76x80 scores (dead after S2)
#define OFF_CTX 25840           // 76x65  (dead after S3)
#define OFF_C2  30780           // 76x65  (dead after S5)
#define POOL_F  35720           // 142,880 bytes
// overlays (lifetimes verified disjoint):
#define OFF_STG OFF_SC          // S1/S3 weight staging (4096 <= 6080)
#define OFF_WS  OFF_EMB         // S4/S5/S6 weight staging (4096 <= 4940)
#define OFF_HID OFF_Q           // 76x260 = 19760 floats, spans Q..SC (S4-S5)
#define OFF_C3  OFF_CTX         // S5 out, used through S7
#define OFF_FK  OFF_C2          // S6 out
#define OFF_FV  OFF_K           // S6 out
#define OFF_SCR OFF_SC          // S7 scratch (hid dead by then)

__device__ __forceinline__ void gemm64p(
    float* pool, int offA, int offW, const float* __restrict__ bg,
    int offR, int offOut, int tid)
{
    // out[76][64] = A[76][64] @ Wlds[64][64] + b (+ residual in LDS)
    for (int idx = tid; idx < FFEAT * 32; idx += 512) {
        int r = idx >> 5, cp = (idx & 31) << 1;
        float2 bv2 = *(const float2*)&bg[cp];
        float ax = bv2.x, ay = bv2.y;
        const float* ar = &pool[offA + r * PSTR];
        const float* wc = &pool[offW + cp];
        #pragma unroll 16
        for (int k = 0; k < 64; ++k) {
            float a = ar[k];                              // LDS broadcast
            float2 w = *(const float2*)&wc[k << 6];       // ds_read_b64, conflict-free
            ax = fmaf(a, w.x, ax);
            ay = fmaf(a, w.y, ay);
        }
        if (offR >= 0) {
            ax += pool[offR + r * PSTR + cp];
            ay += pool[offR + r * PSTR + cp + 1];
        }
        pool[offOut + r * PSTR + cp]     = ax;
        pool[offOut + r * PSTR + cp + 1] = ay;
    }
}

__global__ __launch_bounds__(512, 2) void tail_kernel(
    const float* __restrict__ emb,
    const float* __restrict__ wq, const float* __restrict__ bq,
    const float* __restrict__ wk, const float* __restrict__ bk,
    const float* __restrict__ wv, const float* __restrict__ bv,
    const float* __restrict__ wo, const float* __restrict__ bo,
    const float* __restrict__ w1, const float* __restrict__ b1,
    const float* __restrict__ w2, const float* __restrict__ b2,
    const float* __restrict__ faq, const float* __restrict__ fabq,
    const float* __restrict__ fak, const float* __restrict__ fabk,
    const float* __restrict__ fav, const float* __restrict__ fabv,
    const float* __restrict__ o0w, const float* __restrict__ o0b,
    const float* __restrict__ o1w, const float* __restrict__ o1b,
    float* __restrict__ out)
{
    __shared__ float pool[POOL_F];
    const int b   = blockIdx.x;
    const int tid = threadIdx.x;

    // ---- S0: load emb rows of this batch; stage wq ----
    for (int i = tid; i < FFEAT * HDIM; i += 512) {
        int r = i >> 6, c = i & 63;
        pool[OFF_EMB + r * PSTR + c] = emb[((size_t)b * FFEAT + r) * HDIM + c];
    }
    for (int i = tid; i < 4096; i += 512) pool[OFF_STG + i] = wq[i];
    __syncthreads();

    // ---- S1: q, k, v = emb @ W + b ----
    gemm64p(pool, OFF_EMB, OFF_STG, bq, -1, OFF_Q, tid);
    __syncthreads();
    for (int i = tid; i < 4096; i += 512) pool[OFF_STG + i] = wk[i];
    __syncthreads();
    gemm64p(pool, OFF_EMB, OFF_STG, bk, -1, OFF_K, tid);
    __syncthreads();
    for (int i = tid; i < 4096; i += 512) pool[OFF_STG + i] = wv[i];
    __syncthreads();
    gemm64p(pool, OFF_EMB, OFF_STG, bv, -1, OFF_V, tid);
    __syncthreads();

    // ---- S2: 4-head self-attention over the F axis -> ctx ----
    for (int i = tid; i < FFEAT * PSTR; i += 512) pool[OFF_CTX + i] = 0.f;
    __syncthreads();
    for (int hh = 0; hh < NHEAD; ++hh) {
        const int o = hh * DKH;
        for (int idx = tid; idx < FFEAT * FFEAT; idx += 512) {
            int i = idx / FFEAT, j = idx - i * FFEAT;
            const float* qi = &pool[OFF_Q + i * PSTR + o];
            const float* kj = &pool[OFF_K + j * PSTR + o];
            float acc = 0.f;
            #pragma unroll
            for (int c = 0; c < DKH; ++c) acc = fmaf(qi[c], kj[c], acc);
            pool[OFF_SC + i * 80 + j] = acc * 0.25f;
        }
        __syncthreads();
        if (tid < FFEAT) {
            float* row = &pool[OFF_SC + tid * 80];
            float m = row[0];
            #pragma unroll 4
            for (int j = 1; j < FFEAT; ++j) m = fmaxf(m, row[j]);
            float s = 0.f;
            #pragma unroll 4
            for (int j = 0; j < FFEAT; ++j) {
                float p = __builtin_amdgcn_exp2f((row[j] - m) * LOG2E);
                row[j] = p; s += p;
            }
            float inv = 1.0f / s;
            #pragma unroll 4
            for (int j = 0; j < FFEAT; ++j) row[j] *= inv;
        }
        __syncthreads();
        for (int idx = tid; idx < FFEAT * DKH; idx += 512) {
            int i = idx >> 4, c = idx & 15;
            const float* pr = &pool[OFF_SC + i * 80];
            const float* vc = &pool[OFF_V + o + c];
            float acc = 0.f;
            #pragma unroll 4
            for (int j = 0; j < FFEAT; ++j) acc = fmaf(pr[j], vc[j * PSTR], acc);
            pool[OFF_CTX + i * PSTR + o + c] += acc;
        }
        __syncthreads();
    }

    // ---- S3: ctx2 = emb + ctx @ wo + bo ----
    for (int i = tid; i < 4096; i += 512) pool[OFF_STG + i] = wo[i];
    __syncthreads();
    gemm64p(pool, OFF_CTX, OFF_STG, bo, OFF_EMB, OFF_C2, tid);
    __syncthreads();

    // ---- S4: hid = relu(ctx2 @ w1 + b1), 4 column slabs of 64 ----
    for (int cs = 0; cs < 4; ++cs) {
        for (int i = tid; i < 4096; i += 512) {
            int k = i >> 6, cc = i & 63;
            pool[OFF_WS + i] = w1[(k << 8) + (cs << 6) + cc];
        }
        __syncthreads();
        for (int idx = tid; idx < FFEAT * 32; idx += 512) {
            int r = idx >> 5, cp = (idx & 31) << 1;
            float2 bv2 = *(const float2*)&b1[(cs << 6) + cp];
            float ax = bv2.x, ay = bv2.y;
            const float* ar = &pool[OFF_C2 + r * PSTR];
            const float* wc = &pool[OFF_WS + cp];
            #pragma unroll 16
            for (int k = 0; k < 64; ++k) {
                float a = ar[k];
                float2 w = *(const float2*)&wc[k << 6];
                ax = fmaf(a, w.x, ax);
                ay = fmaf(a, w.y, ay);
            }
            float* hd = &pool[OFF_HID + r * 260 + (cs << 6) + cp];
            hd[0] = fmaxf(ax, 0.f);
            hd[1] = fmaxf(ay, 0.f);
        }
        __syncthreads();
    }

    // ---- S5: ctx3 = ctx2 + hid @ w2 + b2, 4 k-slabs of 64 ----
    for (int ks = 0; ks < 4; ++ks) {
        for (int i = tid; i < 4096; i += 512) pool[OFF_WS + i] = w2[(ks << 12) + i];
        __syncthreads();
        for (int idx = tid; idx < FFEAT * 32; idx += 512) {
            int r = idx >> 5, cp = (idx & 31) << 1;
            float ax, ay;
            if (ks == 0) {
                float2 bv2 = *(const float2*)&b2[cp];
                ax = bv2.x + pool[OFF_C2 + r * PSTR + cp];
                ay = bv2.y + pool[OFF_C2 + r * PSTR + cp + 1];
            } else {
                ax = pool[OFF_C3 + r * PSTR + cp];
                ay = pool[OFF_C3 + r * PSTR + cp + 1];
            }
            const float* hr = &pool[OFF_HID + r * 260 + (ks << 6)];
            const float* wc = &pool[OFF_WS + cp];
            #pragma unroll 16
            for (int k = 0; k < 64; ++k) {
                float a = hr[k];
                float2 w = *(const float2*)&wc[k << 6];
                ax = fmaf(a, w.x, ax);
                ay = fmaf(a, w.y, ay);
            }
            pool[OFF_C3 + r * PSTR + cp]     = ax;
            pool[OFF_C3 + r * PSTR + cp + 1] = ay;
        }
        __syncthreads();
    }

    // ---- S6: fk = ctx3 @ fak + fabk ; fv = ctx3 @ fav + fabv ----
    for (int i = tid; i < 4096; i += 512) pool[OFF_WS + i] = fak[i];
    __syncthreads();
    gemm64p(pool, OFF_C3, OFF_WS, fabk, -1, OFF_FK, tid);
    __syncthreads();
    for (int i = tid; i < 4096; i += 512) pool[OFF_WS + i] = fav[i];
    __syncthreads();
    gemm64p(pool, OFF_C3, OFF_WS, fabv, -1, OFF_FV, tid);
    __syncthreads();

    // ---- S7: final attention + output head ----
    float* SCR = &pool[OFF_SCR];
    if (tid < HDIM) {                        // fq = ctx3[last] @ faq + fabq
        const float* last = &pool[OFF_C3 + 75 * PSTR];
        float acc = fabq[tid];
        #pragma unroll 16
        for (int j = 0; j < HDIM; ++j) acc = fmaf(last[j], faq[(j << 6) + tid], acc);
        SCR[tid] = acc;
    }
    __syncthreads();
    if (tid < FFEAT) {                       // fe[i] = fk[i] . fq
        const float* kr = &pool[OFF_FK + tid * PSTR];
        float acc = 0.f;
        #pragma unroll 16
        for (int c = 0; c < HDIM; ++c) acc = fmaf(kr[c], SCR[c], acc);
        SCR[64 + tid] = acc;
    }
    __syncthreads();
    if (tid == 0) {                          // softmax over 76 (tiny, serial)
        float m = SCR[64];
        for (int i = 1; i < FFEAT; ++i) m = fmaxf(m, SCR[64 + i]);
        float s = 0.f;
        for (int i = 0; i < FFEAT; ++i) {
            float p = __builtin_amdgcn_exp2f((SCR[64 + i] - m) * LOG2E);
            SCR[64 + i] = p; s += p;
        }
        float inv = 1.0f / s;
        for (int i = 0; i < FFEAT; ++i) SCR[64 + i] *= inv;
    }
    __syncthreads();
    if (tid < HDIM) {                        // v = sum_i sm[i] * fv[i]
        float acc = 0.f;
        #pragma unroll 4
        for (int ff = 0; ff < FFEAT; ++ff)
            acc = fmaf(SCR[64 + ff], pool[OFF_FV + ff * PSTR + tid], acc);
        SCR[160 + tid] = acc;
    }
    __syncthreads();
    if (tid < HDIM) {                        // out = sigmoid(relu(v@o0+b0)@o1+b1)
        float acc = o0b[tid];
        #pragma unroll 16
        for (int j = 0; j < HDIM; ++j) acc = fmaf(SCR[160 + j], o0w[(j << 6) + tid], acc);
        float h = fmaxf(acc, 0.f);
        float t = h * o1w[tid];
        #pragma unroll
        for (int off = 32; off > 0; off >>= 1) t += __shfl_xor(t, off, 64);
        if (tid == 0) out[b] = fast_sigmoid(t + o1b[0]);
    }
}

__global__ void ws_report_kernel(float* out, int n, float ws_mib) {
    int i = blockIdx.x * blockDim.x + threadIdx.x;
    if (i < n) out[i] = ws_mib;
}

extern "C" void kernel_launch(void* const* d_in, const int* in_sizes, int n_in,
                              void* d_out, int out_size, void* d_ws, size_t ws_size,
                              hipStream_t stream)
{
    const float* x     = (const float*)d_in[0];
    const float* w_ih  = (const float*)d_in[1];
    const float* w_hh  = (const float*)d_in[2];
    const float* b_ih  = (const float*)d_in[3];
    const float* b_hh  = (const float*)d_in[4];
    const float* attWt = (const float*)d_in[5];
    const float* attWx = (const float*)d_in[6];
    const float* attRt = (const float*)d_in[7];
    const float* wq    = (const float*)d_in[8];
    const float* bq    = (const float*)d_in[9];
    const float* wk    = (const float*)d_in[10];
    const float* bk    = (const float*)d_in[11];
    const float* wv    = (const float*)d_in[12];
    const float* bv    = (const float*)d_in[13];
    const float* wo    = (const float*)d_in[14];
    const float* bo    = (const float*)d_in[15];
    const float* w1    = (const float*)d_in[16];
    const float* b1    = (const float*)d_in[17];
    const float* w2    = (const float*)d_in[18];
    const float* b2    = (const float*)d_in[19];
    const float* faq   = (const float*)d_in[20];
    const float* fabq  = (const float*)d_in[21];
    const float* fak   = (const float*)d_in[22];
    const float* fabk  = (const float*)d_in[23];
    const float* fav   = (const float*)d_in[24];
    const float* fabv  = (const float*)d_in[25];
    const float* o0w   = (const float*)d_in[26];
    const float* o0b   = (const float*)d_in[27];
    const float* o1w   = (const float*)d_in[28];
    const float* o1b   = (const float*)d_in[29];
    float* out = (float*)d_out;

    const size_t emb_bytes  = (size_t)NROWS * HDIM * 4;
    const size_t wtil_bytes = (size_t)NROWS * HDIM * 4;

    // Only hs remains as scratch (tail intermediates now live in LDS).
    const int chunk_opts[6] = {76, 38, 19, 4, 2, 1};
    int FC = 0;
    for (int i = 0; i < 6; ++i) {
        size_t hs_b = (size_t)chunk_opts[i] * BBATCH * TT * HDIM * 2;
        if (emb_bytes + wtil_bytes + hs_b <= ws_size) { FC = chunk_opts[i]; break; }
    }
    if (FC == 0) {
        ws_report_kernel<<<dim3((out_size + 255) / 256), dim3(256), 0, stream>>>(
            out, out_size, (float)((double)ws_size / (1024.0 * 1024.0)));
        return;
    }

    float* emb  = (float*)d_ws;
    float* wtil = (float*)((char*)d_ws + emb_bytes);
    __hip_bfloat16* hs = (__hip_bfloat16*)((char*)d_ws + emb_bytes + wtil_bytes);

    for (int f0 = 0; f0 < FFEAT; f0 += FC) {
        int fc = (FFEAT - f0 < FC) ? (FFEAT - f0) : FC;
        gru_scan_kernel<<<dim3(4, fc), dim3(256), 0, stream>>>(
            x, w_ih, w_hh, b_ih, b_hh, attWt, attWx, f0, hs, wtil);
        attn2_kernel<<<dim3(BBATCH, fc), dim3(64), 0, stream>>>(
            hs, wtil, attRt, f0, emb);
    }

    tail_kernel<<<dim3(BBATCH), dim3(512), 0, stream>>>(
        emb, wq, bq, wk, bk, wv, bv, wo, bo,
        w1, b1, w2, b2, faq, fabq, fak, fabk, fav, fabv,
        o0w, o0b, o1w, o1b, out);
}